// Round 5
// baseline (2845.564 us; speedup 1.0000x reference)
//
#include <hip/hip_runtime.h>

#define B_  128
#define T_  4096
#define F_  64
#define H_  128
#define NT  256   // 4 waves; wave w owns cols 32w..32w+31 of each gate

typedef _Float16 half8_t __attribute__((ext_vector_type(8)));
typedef _Float16 half2_t __attribute__((ext_vector_type(2)));
typedef float    f32x4   __attribute__((ext_vector_type(4)));

__device__ __forceinline__ half2_t pack2(float a, float b) {
  half2_t r; r[0] = (_Float16)a; r[1] = (_Float16)b; return r;
}

// LDS-only barrier: __syncthreads would drain vmcnt(0) and stall on the
// in-flight x prefetch; we only need LDS ordering.
__device__ __forceinline__ void wg_barrier() {
  __asm__ volatile("s_waitcnt lgkmcnt(0)\n\ts_barrier" ::: "memory");
}

__device__ __forceinline__ float fast_sigmoid(float x) {
  float e = __builtin_amdgcn_exp2f(x * -1.4426950408889634f);
  return __builtin_amdgcn_rcpf(1.0f + e);
}
__device__ __forceinline__ float fast_tanh(float x) {
  float e = __builtin_amdgcn_exp2f(x * -2.8853900817779268f);
  return 2.0f * __builtin_amdgcn_rcpf(1.0f + e) - 1.0f;
}

// Per step (iter t): act(acc_t) -> h_t; write h_t; START acc_{t+1} with the
// x-part mfmas (no h dependency -> pre-barrier); barrier; read h_t frags;
// finish acc_{t+1} with the 4-deep h-part mfma chains.
__global__ __launch_bounds__(NT, 1) void lstm_mfma4_kernel(
    const float* __restrict__ X,    // [B, T, F]
    const float* __restrict__ Wih,  // [4H, F]
    const float* __restrict__ Whh,  // [4H, H]
    const float* __restrict__ bih,  // [4H]
    const float* __restrict__ bhh,  // [4H]
    float* __restrict__ out)        // [B, H]
{
  const int tid  = threadIdx.x;
  const int b    = blockIdx.x;
  const int lane = tid & 63;
  const int w    = tid >> 6;     // wave 0..3
  const int lg   = lane >> 4;    // k-group 0..3
  const int lc   = lane & 15;    // col-in-16

  __shared__ __align__(16) _Float16 hbuf[2][H_];   // h ring (f16)
  __shared__ __align__(16) _Float16 xbuf[4][F_];   // x ring (f16)

  // ---- B-frags: Wf[g][n][c]; lane holds W[128g + 32w + 16n + lc][k],
  // k = 32c + 8*lg + j (c=0..3 -> Whh, c=4..5 -> Wih), f32 -> f16.
  half8_t Wf[4][2][6];
  float   bias_v[4][2];
#pragma unroll
  for (int g = 0; g < 4; ++g) {
#pragma unroll
    for (int n = 0; n < 2; ++n) {
      const int row = 128 * g + 32 * w + 16 * n + lc;
      bias_v[g][n] = bih[row] + bhh[row];
#pragma unroll
      for (int c = 0; c < 6; ++c) {
        const float* src = (c < 4) ? (Whh + (size_t)row * H_ + 32 * c + 8 * lg)
                                   : (Wih + (size_t)row * F_ + 32 * (c - 4) + 8 * lg);
        float4 lo = *(const float4*)(src);
        float4 hi = *(const float4*)(src + 4);
        half8_t v;
        v[0] = (_Float16)lo.x; v[1] = (_Float16)lo.y;
        v[2] = (_Float16)lo.z; v[3] = (_Float16)lo.w;
        v[4] = (_Float16)hi.x; v[5] = (_Float16)hi.y;
        v[6] = (_Float16)hi.z; v[7] = (_Float16)hi.w;
        Wf[g][n][c] = v;
      }
    }
  }

  // ---- x stager: wave 3, lanes 0..31 (these lanes also compute)
  const bool   stager = (w == 3) && (lane < 32);
  const float* xbase  = X + (size_t)b * T_ * F_;
  float2 xq0, xq1;
  if (stager) {
    float2 a0 = ((const float2*)(xbase + 0 * F_))[lane];
    float2 a1 = ((const float2*)(xbase + 1 * F_))[lane];
    float2 a2 = ((const float2*)(xbase + 2 * F_))[lane];
    *(half2_t*)&xbuf[0][2 * lane] = pack2(a0.x, a0.y);
    *(half2_t*)&xbuf[1][2 * lane] = pack2(a1.x, a1.y);
    *(half2_t*)&xbuf[2][2 * lane] = pack2(a2.x, a2.y);
    xq0 = ((const float2*)(xbase + 3 * F_))[lane];   // x[3]
    xq1 = ((const float2*)(xbase + 4 * F_))[lane];   // x[4]
  }

  wg_barrier();   // x[0] visible

  // ---- prologue = "iter -1": acc_0 = x-part(x[0]); h_{-1}=0 so no h-part
  const f32x4 z = {0.0f, 0.0f, 0.0f, 0.0f};
  f32x4 acc[4][2];
  {
    half8_t ax0 = *(const half8_t*)&xbuf[0][8 * lg];
    half8_t ax1 = *(const half8_t*)&xbuf[0][32 + 8 * lg];
#pragma unroll
    for (int g = 0; g < 4; ++g)
#pragma unroll
      for (int n = 0; n < 2; ++n) {
        f32x4 a = __builtin_amdgcn_mfma_f32_16x16x32_f16(ax0, Wf[g][n][4], z, 0, 0, 0);
        acc[g][n] = __builtin_amdgcn_mfma_f32_16x16x32_f16(ax1, Wf[g][n][5], a, 0, 0, 0);
      }
  }

  float c0 = 0.0f, c1 = 0.0f, hl0 = 0.0f, hl1 = 0.0f;

#pragma unroll 2
  for (int t = 0; t < T_; ++t) {
    const int nbuf = t & 1;

    // ---- activation: acc holds preact(t); two columns per lane (n=0,1)
    float i0 = fast_sigmoid(acc[0][0][0] + bias_v[0][0]);
    float f0 = fast_sigmoid(acc[1][0][0] + bias_v[1][0]);
    float g0 = fast_tanh   (acc[2][0][0] + bias_v[2][0]);
    float o0 = fast_sigmoid(acc[3][0][0] + bias_v[3][0]);
    float i1 = fast_sigmoid(acc[0][1][0] + bias_v[0][1]);
    float f1 = fast_sigmoid(acc[1][1][0] + bias_v[1][1]);
    float g1 = fast_tanh   (acc[2][1][0] + bias_v[2][1]);
    float o1 = fast_sigmoid(acc[3][1][0] + bias_v[3][1]);

    c0 = f0 * c0 + i0 * g0;
    c1 = f1 * c1 + i1 * g1;
    float h0 = o0 * fast_tanh(c0);
    float h1 = o1 * fast_tanh(c1);
    hl0 = h0; hl1 = h1;

    // h_t -> LDS: lanes 0..31 cover cols 32w..32w+31 (rows redundant)
    if (lane < 32) hbuf[nbuf][32 * w + lane] = (_Float16)(lane < 16 ? h0 : h1);

    // ---- start acc_{t+1}: x-part (slot (t+1)&3, staged 2+ steps ago)
    {
      const int s1 = (t + 1) & 3;
      half8_t ax0 = *(const half8_t*)&xbuf[s1][8 * lg];
      half8_t ax1 = *(const half8_t*)&xbuf[s1][32 + 8 * lg];
#pragma unroll
      for (int g = 0; g < 4; ++g)
#pragma unroll
        for (int n = 0; n < 2; ++n) {
          f32x4 a = __builtin_amdgcn_mfma_f32_16x16x32_f16(ax0, Wf[g][n][4], z, 0, 0, 0);
          acc[g][n] = __builtin_amdgcn_mfma_f32_16x16x32_f16(ax1, Wf[g][n][5], a, 0, 0, 0);
        }
    }

    // ---- stager: write x[t+3] -> slot (t+3)&3, load x[t+5]
    if (stager) {
      int nu = t + 5; nu = (nu < T_) ? nu : (T_ - 1);
      const float2* xrn = (const float2*)(xbase + (size_t)nu * F_);
      if ((t & 1) == 0) {            // static under unroll-2
        *(half2_t*)&xbuf[(t + 3) & 3][2 * lane] = pack2(xq0.x, xq0.y);
        xq0 = xrn[lane];
      } else {
        *(half2_t*)&xbuf[(t + 3) & 3][2 * lane] = pack2(xq1.x, xq1.y);
        xq1 = xrn[lane];
      }
    }

    wg_barrier();   // h_t visible

    // ---- finish acc_{t+1}: h-part, 8 independent 4-deep chains
    half8_t ah[4];
#pragma unroll
    for (int c = 0; c < 4; ++c)
      ah[c] = *(const half8_t*)&hbuf[nbuf][32 * c + 8 * lg];
#pragma unroll
    for (int c = 0; c < 4; ++c)
#pragma unroll
      for (int g = 0; g < 4; ++g)
#pragma unroll
        for (int n = 0; n < 2; ++n)
          acc[g][n] = __builtin_amdgcn_mfma_f32_16x16x32_f16(ah[c], Wf[g][n][c],
                                                             acc[g][n], 0, 0, 0);
  }

  if (lane < 32) out[(size_t)b * H_ + 32 * w + lane] = (lane < 16 ? hl0 : hl1);
}

extern "C" void kernel_launch(void* const* d_in, const int* in_sizes, int n_in,
                              void* d_out, int out_size, void* d_ws, size_t ws_size,
                              hipStream_t stream) {
  const float* X   = (const float*)d_in[0];
  const float* Wih = (const float*)d_in[1];
  const float* Whh = (const float*)d_in[2];
  const float* bih = (const float*)d_in[3];
  const float* bhh = (const float*)d_in[4];
  float* out = (float*)d_out;

  lstm_mfma4_kernel<<<dim3(B_), dim3(NT), 0, stream>>>(X, Wih, Whh, bih, bhh, out);
}

// Round 6
// 2399.953 us; speedup vs baseline: 1.1857x; 1.1857x over previous
//
#include <hip/hip_runtime.h>

#define B_  128
#define T_  4096
#define F_  64
#define H_  128
#define NT  512   // 8 waves; wave w owns cols 16w..16w+15 of each gate

typedef _Float16 half8_t __attribute__((ext_vector_type(8)));
typedef _Float16 half2_t __attribute__((ext_vector_type(2)));
typedef float    f32x4   __attribute__((ext_vector_type(4)));

__device__ __forceinline__ half2_t pack2(float a, float b) {
  half2_t r; r[0] = (_Float16)a; r[1] = (_Float16)b; return r;
}

// LDS-only barrier: __syncthreads would drain vmcnt(0) and stall on the
// in-flight x prefetch; we only need LDS ordering.
__device__ __forceinline__ void wg_barrier() {
  __asm__ volatile("s_waitcnt lgkmcnt(0)\n\ts_barrier" ::: "memory");
}

__device__ __forceinline__ float fast_sigmoid(float x) {
  float e = __builtin_amdgcn_exp2f(x * -1.4426950408889634f);
  return __builtin_amdgcn_rcpf(1.0f + e);
}
__device__ __forceinline__ float fast_tanh(float x) {
  float e = __builtin_amdgcn_exp2f(x * -2.8853900817779268f);
  return 2.0f * __builtin_amdgcn_rcpf(1.0f + e) - 1.0f;
}

// 8 waves (2/SIMD for latency hiding), 16 cols/wave of each gate.
// Iter t: act(pre_t) -> h_t -> LDS; start pre_{t+1} with x-part mfmas
// (bias as C-init); distributed x staging; barrier; 4 h-frag reads;
// finish pre_{t+1} with two parallel 2-deep h-mfma chains per gate.
__global__ __launch_bounds__(NT, 2) void lstm_mfma8_kernel(
    const float* __restrict__ X,    // [B, T, F]
    const float* __restrict__ Wih,  // [4H, F]
    const float* __restrict__ Whh,  // [4H, H]
    const float* __restrict__ bih,  // [4H]
    const float* __restrict__ bhh,  // [4H]
    float* __restrict__ out)        // [B, H]
{
  const int tid  = threadIdx.x;
  const int b    = blockIdx.x;
  const int lane = tid & 63;
  const int w    = tid >> 6;     // wave 0..7
  const int lg   = lane >> 4;    // k-group 0..3
  const int lc   = lane & 15;    // col-in-16

  __shared__ __align__(16) _Float16 hbuf[2][H_];   // h ring (f16)
  __shared__ __align__(16) _Float16 xbuf[4][F_];   // x ring (f16)

  // ---- B-frags: Wf[g][c]; lane holds W[128g + 16w + lc][32c + 8lg + j],
  // j=0..7 (c=0..3 -> Whh, c=4..5 -> Wih), f32 -> f16. Bias -> x-chain C-init.
  half8_t Wf[4][6];
  f32x4   xinit[4];
#pragma unroll
  for (int g = 0; g < 4; ++g) {
    const int row = 128 * g + 16 * w + lc;
    const float bv = bih[row] + bhh[row];
    f32x4 bi = {bv, bv, bv, bv};
    xinit[g] = bi;
#pragma unroll
    for (int c = 0; c < 6; ++c) {
      const float* src = (c < 4) ? (Whh + (size_t)row * H_ + 32 * c + 8 * lg)
                                 : (Wih + (size_t)row * F_ + 32 * (c - 4) + 8 * lg);
      float4 lo = *(const float4*)(src);
      float4 hi = *(const float4*)(src + 4);
      half8_t v;
      v[0] = (_Float16)lo.x; v[1] = (_Float16)lo.y;
      v[2] = (_Float16)lo.z; v[3] = (_Float16)lo.w;
      v[4] = (_Float16)hi.x; v[5] = (_Float16)hi.y;
      v[6] = (_Float16)hi.z; v[7] = (_Float16)hi.w;
      Wf[g][c] = v;
    }
  }

  // ---- distributed x stager: every wave, lanes 0..3; position p = 4w+lane
  const bool   stg = (lane < 4);
  const int    p   = 4 * w + lane;        // 0..31 float2 positions
  const float* xbase = X + (size_t)b * T_ * F_;
  float2 xq0, xq1;
  if (stg) {
    float2 a0 = ((const float2*)(xbase + 0 * F_))[p];
    float2 a1 = ((const float2*)(xbase + 1 * F_))[p];
    float2 a2 = ((const float2*)(xbase + 2 * F_))[p];
    *(half2_t*)&xbuf[0][2 * p] = pack2(a0.x, a0.y);
    *(half2_t*)&xbuf[1][2 * p] = pack2(a1.x, a1.y);
    *(half2_t*)&xbuf[2][2 * p] = pack2(a2.x, a2.y);
    xq0 = ((const float2*)(xbase + 3 * F_))[p];   // x[3]
    xq1 = ((const float2*)(xbase + 4 * F_))[p];   // x[4]
  }

  wg_barrier();   // x[0..2] visible

  // ---- prologue: pre_0 = bias + Wih.x_0  (h_{-1}=0)
  const f32x4 zf = {0.0f, 0.0f, 0.0f, 0.0f};
  f32x4 pre[4], pB[4], xpre[4];
  {
    half8_t ax0 = *(const half8_t*)&xbuf[0][8 * lg];
    half8_t ax1 = *(const half8_t*)&xbuf[0][32 + 8 * lg];
#pragma unroll
    for (int g = 0; g < 4; ++g) {
      f32x4 a = __builtin_amdgcn_mfma_f32_16x16x32_f16(ax0, Wf[g][4], xinit[g], 0, 0, 0);
      pre[g]  = __builtin_amdgcn_mfma_f32_16x16x32_f16(ax1, Wf[g][5], a, 0, 0, 0);
      pB[g]   = zf;
    }
  }

  float cs = 0.0f, hl = 0.0f;

#pragma unroll 2
  for (int t = 0; t < T_; ++t) {
    // ---- activation: preact_t = pre + pB (element 0; all row-groups identical)
    float si = fast_sigmoid(pre[0][0] + pB[0][0]);
    float sf = fast_sigmoid(pre[1][0] + pB[1][0]);
    float sg = fast_tanh   (pre[2][0] + pB[2][0]);
    float so = fast_sigmoid(pre[3][0] + pB[3][0]);

    cs = sf * cs + si * sg;
    float hn = so * fast_tanh(cs);
    hl = hn;

    if (lane < 16) hbuf[t & 1][16 * w + lc] = (_Float16)hn;

    // ---- start pre_{t+1}: x-part (slot staged >=2 iters ago), bias C-init
    {
      const int s1 = (t + 1) & 3;
      half8_t ax0 = *(const half8_t*)&xbuf[s1][8 * lg];
      half8_t ax1 = *(const half8_t*)&xbuf[s1][32 + 8 * lg];
#pragma unroll
      for (int g = 0; g < 4; ++g) {
        f32x4 a = __builtin_amdgcn_mfma_f32_16x16x32_f16(ax0, Wf[g][4], xinit[g], 0, 0, 0);
        xpre[g] = __builtin_amdgcn_mfma_f32_16x16x32_f16(ax1, Wf[g][5], a, 0, 0, 0);
      }
    }

    // ---- distributed staging: write x[t+3] -> slot (t+3)&3, load x[t+5]
    if (stg) {
      int nu = t + 5; nu = (nu < T_) ? nu : (T_ - 1);
      const float2* xrn = (const float2*)(xbase + (size_t)nu * F_);
      if ((t & 1) == 0) {            // static under unroll-2
        *(half2_t*)&xbuf[(t + 3) & 3][2 * p] = pack2(xq0.x, xq0.y);
        xq0 = xrn[p];
      } else {
        *(half2_t*)&xbuf[(t + 3) & 3][2 * p] = pack2(xq1.x, xq1.y);
        xq1 = xrn[p];
      }
    }

    wg_barrier();   // h_t (+ staged x) visible

    // ---- finish pre_{t+1}: h-part, two parallel 2-deep chains per gate
    half8_t ah0 = *(const half8_t*)&hbuf[t & 1][ 0 + 8 * lg];
    half8_t ah1 = *(const half8_t*)&hbuf[t & 1][32 + 8 * lg];
    half8_t ah2 = *(const half8_t*)&hbuf[t & 1][64 + 8 * lg];
    half8_t ah3 = *(const half8_t*)&hbuf[t & 1][96 + 8 * lg];
#pragma unroll
    for (int g = 0; g < 4; ++g) {
      f32x4 a  = __builtin_amdgcn_mfma_f32_16x16x32_f16(ah0, Wf[g][0], xpre[g], 0, 0, 0);
      pre[g]   = __builtin_amdgcn_mfma_f32_16x16x32_f16(ah1, Wf[g][1], a, 0, 0, 0);
      f32x4 a2 = __builtin_amdgcn_mfma_f32_16x16x32_f16(ah2, Wf[g][2], zf, 0, 0, 0);
      pB[g]    = __builtin_amdgcn_mfma_f32_16x16x32_f16(ah3, Wf[g][3], a2, 0, 0, 0);
    }
  }

  if (lane < 16) out[(size_t)b * H_ + 16 * w + lc] = hl;
}

extern "C" void kernel_launch(void* const* d_in, const int* in_sizes, int n_in,
                              void* d_out, int out_size, void* d_ws, size_t ws_size,
                              hipStream_t stream) {
  const float* X   = (const float*)d_in[0];
  const float* Wih = (const float*)d_in[1];
  const float* Whh = (const float*)d_in[2];
  const float* bih = (const float*)d_in[3];
  const float* bhh = (const float*)d_in[4];
  float* out = (float*)d_out;

  lstm_mfma8_kernel<<<dim3(B_), dim3(NT), 0, stream>>>(X, Wih, Whh, bih, bhh, out);
}

// Round 7
// 1946.556 us; speedup vs baseline: 1.4618x; 1.2329x over previous
//
#include <hip/hip_runtime.h>

#define B_  128
#define T_  4096
#define F_  64
#define H_  128
#define NT  512   // 8 waves; wave w owns cols 16w..16w+15 of each gate

typedef _Float16 half8_t __attribute__((ext_vector_type(8)));
typedef _Float16 half2_t __attribute__((ext_vector_type(2)));
typedef float    f32x4   __attribute__((ext_vector_type(4)));

__device__ __forceinline__ half2_t pack2(float a, float b) {
  half2_t r; r[0] = (_Float16)a; r[1] = (_Float16)b; return r;
}

// LDS-only barrier (no vmcnt drain; global x loads stay in flight).
__device__ __forceinline__ void wg_barrier() {
  __asm__ volatile("s_waitcnt lgkmcnt(0)\n\ts_barrier" ::: "memory");
}

__device__ __forceinline__ float fast_sigmoid(float x) {
  float e = __builtin_amdgcn_exp2f(x * -1.4426950408889634f);
  return __builtin_amdgcn_rcpf(1.0f + e);
}
__device__ __forceinline__ float fast_tanh(float x) {
  float e = __builtin_amdgcn_exp2f(x * -2.8853900817779268f);
  return 2.0f * __builtin_amdgcn_rcpf(1.0f + e) - 1.0f;
}

// Per step only the h-part (16 mfma/wave). Wih*x + bias is batched over time:
// every 16 steps one M=16 (16 timesteps, full M) GEMM -> xg in LDS (fp32).
// Pipeline over period P: consume xg(P); GEMM xg(P+1) at tau==0 (from xstage
// staged last period); global-load X(P+2) at tau==0, LDS-stage it at tau==8.
__global__ __launch_bounds__(NT, 2) void lstm_xg_kernel(
    const float* __restrict__ X,    // [B, T, F]
    const float* __restrict__ Wih,  // [4H, F]
    const float* __restrict__ Whh,  // [4H, H]
    const float* __restrict__ bih,  // [4H]
    const float* __restrict__ bhh,  // [4H]
    float* __restrict__ out)        // [B, H]
{
  const int tid  = threadIdx.x;
  const int b    = blockIdx.x;
  const int lane = tid & 63;
  const int w    = tid >> 6;     // wave 0..7
  const int lg   = lane >> 4;    // k-group / tau-group 0..3
  const int lc   = lane & 15;    // col-in-16 (also tau row in batch GEMM A)

  __shared__ __align__(16) _Float16 hbuf[2][H_];        // h ring (f16)
  __shared__ __align__(16) _Float16 xst[2][16 * 72];    // staged x, 16 tau x 64 (+8 pad) f16
  __shared__ __align__(16) float    xg[2][16 * 512];    // xg[tau][col][gate] fp32, 32 KB each

  // ---- B-frags: Wf[g][c]; lane holds W[128g + 16w + lc][32c + 8lg + j],
  // j=0..7 (c=0..3 -> Whh, c=4..5 -> Wih), f32 -> f16.
  half8_t Wf[4][6];
  f32x4   xinit[4];   // bias, C-init of the batch GEMM (same for all tau rows)
#pragma unroll
  for (int g = 0; g < 4; ++g) {
    const int row = 128 * g + 16 * w + lc;
    const float bv = bih[row] + bhh[row];
    f32x4 bi = {bv, bv, bv, bv};
    xinit[g] = bi;
#pragma unroll
    for (int c = 0; c < 6; ++c) {
      const float* src = (c < 4) ? (Whh + (size_t)row * H_ + 32 * c + 8 * lg)
                                 : (Wih + (size_t)row * F_ + 32 * (c - 4) + 8 * lg);
      float4 lo = *(const float4*)(src);
      float4 hi = *(const float4*)(src + 4);
      half8_t v;
      v[0] = (_Float16)lo.x; v[1] = (_Float16)lo.y;
      v[2] = (_Float16)lo.z; v[3] = (_Float16)lo.w;
      v[4] = (_Float16)hi.x; v[5] = (_Float16)hi.y;
      v[6] = (_Float16)hi.z; v[7] = (_Float16)hi.w;
      Wf[g][c] = v;
    }
  }

  const float* xbase = X + (size_t)b * T_ * F_;
  const int    tp    = tid >> 5;   // tau row this thread stages
  const int    kp    = tid & 31;   // f32-pair within row

  // ---- prologue: stage X(period 0) and X(period 1) to LDS f16
  {
    float2 v0 = ((const float2*)xbase)[0 * 512 + tid];
    float2 v1 = ((const float2*)xbase)[1 * 512 + tid];
    *(half2_t*)&xst[0][tp * 72 + 2 * kp] = pack2(v0.x, v0.y);
    *(half2_t*)&xst[1][tp * 72 + 2 * kp] = pack2(v1.x, v1.y);
  }
  wg_barrier();   // xst[0], xst[1] visible

  const f32x4 zf = {0.0f, 0.0f, 0.0f, 0.0f};

  // ---- GEMM xg(0) from xst[0] -> xg[0]
  {
    half8_t a0 = *(const half8_t*)&xst[0][lc * 72 + 8 * lg];        // k=0..31 slice
    half8_t a1 = *(const half8_t*)&xst[0][lc * 72 + 32 + 8 * lg];   // k=32..63 slice
#pragma unroll
    for (int g = 0; g < 4; ++g) {
      f32x4 ab = __builtin_amdgcn_mfma_f32_16x16x32_f16(a0, Wf[g][4], xinit[g], 0, 0, 0);
      ab       = __builtin_amdgcn_mfma_f32_16x16x32_f16(a1, Wf[g][5], ab, 0, 0, 0);
      // stash per-gate rows via regs; write after all gates to pack gate-contiguous
      if (g == 0) { xinit[0] = xinit[0]; }  // no-op, keep structure simple
      // store row r: tau = 4lg + r, col 16w+lc, gate g
#pragma unroll
      for (int r = 0; r < 4; ++r)
        xg[0][(4 * lg + r) * 512 + (16 * w + lc) * 4 + g] = ab[r];
    }
  }
  wg_barrier();   // xg[0] visible

  f32x4 pre[4], pB[4];
#pragma unroll
  for (int g = 0; g < 4; ++g) { pre[g] = zf; pB[g] = zf; }
  f32x4 xg4 = *(const f32x4*)&xg[0][0 * 512 + (16 * w + lc) * 4];   // xg for t=0

  float cs = 0.0f, hl = 0.0f;
  float2 xv = {0.0f, 0.0f};

#pragma unroll 2
  for (int t = 0; t < T_; ++t) {
    const int buf = t & 1;
    const int P   = t >> 4;
    const int tau = t & 15;

    // ---- activation: preact = h-part (pre+pB) + xg (has bias folded in)
    float si = fast_sigmoid(pre[0][0] + pB[0][0] + xg4[0]);
    float sf = fast_sigmoid(pre[1][0] + pB[1][0] + xg4[1]);
    float sg = fast_tanh   (pre[2][0] + pB[2][0] + xg4[2]);
    float so = fast_sigmoid(pre[3][0] + pB[3][0] + xg4[3]);

    cs = sf * cs + si * sg;
    float hn = so * fast_tanh(cs);
    hl = hn;

    if (lane < 16) hbuf[buf][16 * w + lc] = (_Float16)hn;

    // ---- period work (wave-uniform branches)
    if (tau == 0) {
      // batch GEMM xg(P+1) from xst[(P+1)&1] -> xg[(P+1)&1]
      const int sb = (P + 1) & 1;
      half8_t a0 = *(const half8_t*)&xst[sb][lc * 72 + 8 * lg];
      half8_t a1 = *(const half8_t*)&xst[sb][lc * 72 + 32 + 8 * lg];
#pragma unroll
      for (int g = 0; g < 4; ++g) {
        f32x4 ab = __builtin_amdgcn_mfma_f32_16x16x32_f16(a0, Wf[g][4], xinit[g], 0, 0, 0);
        ab       = __builtin_amdgcn_mfma_f32_16x16x32_f16(a1, Wf[g][5], ab, 0, 0, 0);
#pragma unroll
        for (int r = 0; r < 4; ++r)
          xg[sb][(4 * lg + r) * 512 + (16 * w + lc) * 4 + g] = ab[r];
      }
      // issue global loads for X(P+2); consumed at tau==8
      int Pn = P + 2; if (Pn > (T_ / 16 - 1)) Pn = T_ / 16 - 1;
      xv = ((const float2*)xbase)[(size_t)Pn * 512 + tid];
    }
    if (tau == 8) {
      // stage X(P+2) (loaded at tau==0) into xst[P&1] (X(P) is dead)
      *(half2_t*)&xst[P & 1][tp * 72 + 2 * kp] = pack2(xv.x, xv.y);
    }

    wg_barrier();   // h_t (+ any xg/xst writes) visible

    // ---- post-barrier: h-frag reads + xg prefetch for t+1 + 16 h-mfmas
    half8_t ah0 = *(const half8_t*)&hbuf[buf][ 0 + 8 * lg];
    half8_t ah1 = *(const half8_t*)&hbuf[buf][32 + 8 * lg];
    half8_t ah2 = *(const half8_t*)&hbuf[buf][64 + 8 * lg];
    half8_t ah3 = *(const half8_t*)&hbuf[buf][96 + 8 * lg];

    const int tn = t + 1;
    xg4 = *(const f32x4*)&xg[(tn >> 4) & 1][(tn & 15) * 512 + (16 * w + lc) * 4];

#pragma unroll
    for (int g = 0; g < 4; ++g) {
      f32x4 a  = __builtin_amdgcn_mfma_f32_16x16x32_f16(ah0, Wf[g][0], zf, 0, 0, 0);
      pre[g]   = __builtin_amdgcn_mfma_f32_16x16x32_f16(ah1, Wf[g][1], a, 0, 0, 0);
      f32x4 a2 = __builtin_amdgcn_mfma_f32_16x16x32_f16(ah2, Wf[g][2], zf, 0, 0, 0);
      pB[g]    = __builtin_amdgcn_mfma_f32_16x16x32_f16(ah3, Wf[g][3], a2, 0, 0, 0);
    }
  }

  if (lane < 16) out[(size_t)b * H_ + 16 * w + lc] = hl;
}

extern "C" void kernel_launch(void* const* d_in, const int* in_sizes, int n_in,
                              void* d_out, int out_size, void* d_ws, size_t ws_size,
                              hipStream_t stream) {
  const float* X   = (const float*)d_in[0];
  const float* Wih = (const float*)d_in[1];
  const float* Whh = (const float*)d_in[2];
  const float* bih = (const float*)d_in[3];
  const float* bhh = (const float*)d_in[4];
  float* out = (float*)d_out;

  lstm_xg_kernel<<<dim3(B_), dim3(NT), 0, stream>>>(X, Wih, Whh, bih, bhh, out);
}